// Round 2
// baseline (501.903 us; speedup 1.0000x reference)
//
#include <hip/hip_runtime.h>
#include <cstdint>

// VQ forward on MI355X.
// dist argmin via 3-term fp16-split MFMA GEMM (error ~1e-5 absolute), fused
// argmin + runner-up margin tracking + values gather + loss + usage histogram.
// Rows with argmin margin < TAU are re-resolved exactly in fp64 by vq_refine.
//
// ws layout (from d_ws):
//   ehf : [32 chunks][16 ksteps][512] _Float16  (frag-linear)   512 KB
//   elf : same, lo*4096                                          512 KB
//   e2  : [1024] float (fp64-accurate sum of squares)            4 KB
//   flag_cnt : int (+pad)                                        8 B
//   flags    : int2[FCAP] {row, old_idx}                         64 KB

#define D 256
#define NCW 1024
#define CHUNK 32
#define NCHUNK 32
#define NK 16            // 256 / 16 k per mfma
#define TAU 0.00390625f  // margin threshold for fp64 refinement
#define FCAP 8192

typedef _Float16 f16x8 __attribute__((ext_vector_type(8)));
typedef float f32x16 __attribute__((ext_vector_type(16)));
typedef unsigned int u32;
typedef const u32 __attribute__((address_space(1)))* as1_u32p;
typedef u32 __attribute__((address_space(3)))* as3_u32p;

__device__ __forceinline__ void gl_lds16(const void* g, void* s) {
  // global -> LDS direct, 16B per lane. LDS dest is wave-uniform base + lane*16.
  __builtin_amdgcn_global_load_lds((as1_u32p)(uintptr_t)g,
                                   (as3_u32p)(uint32_t)(uintptr_t)s, 16, 0, 0);
}

// ---------------- prep: split embedding into frag-ordered hi/lo + e2 ----------------
__global__ __launch_bounds__(256) void vq_prep(const float* __restrict__ emb,
                                               _Float16* __restrict__ ehf,
                                               _Float16* __restrict__ elf,
                                               float* __restrict__ e2) {
  const int w = threadIdx.x >> 6, l = threadIdx.x & 63;
  const int cw = blockIdx.x * 4 + w;           // 256 blocks * 4 waves = 1024 cw
  const float4 v4 = *(const float4*)(emb + (size_t)cw * D + l * 4);
  const float vv[4] = {v4.x, v4.y, v4.z, v4.w};
  const int chunk = cw >> 5, col = cw & 31;
  double s = 0.0;
#pragma unroll
  for (int i = 0; i < 4; ++i) {
    float v = vv[i];
    s += (double)v * (double)v;
    _Float16 h = (_Float16)v;
    float r = v - (float)h;
    _Float16 lo = (_Float16)(r * 4096.0f);
    int k = l * 4 + i;
    int kk = k >> 4, sub = k & 15;
    int fl = col + ((sub >> 3) << 5);          // frag lane
    int j = sub & 7;
    size_t off = ((size_t)chunk * NK + kk) * 512 + (size_t)fl * 8 + j;
    ehf[off] = h;
    elf[off] = lo;
  }
#pragma unroll
  for (int sft = 1; sft < 64; sft <<= 1) s += __shfl_xor(s, sft);
  if (l == 0) e2[cw] = (float)s;
}

// ---------------- main: GEMM + argmin(+margin) + outputs ----------------
__global__ __launch_bounds__(256, 2) void vq_main(
    const float* __restrict__ x, const float* __restrict__ emb,
    const _Float16* __restrict__ ehf, const _Float16* __restrict__ elf,
    const float* __restrict__ e2g,
    float* __restrict__ out_val, float* __restrict__ out_idx,
    float* __restrict__ out_loss, float* __restrict__ out_usage,
    int* __restrict__ flag_cnt, int2* __restrict__ flags) {
  __shared__ _Float16 eb[2][2][NK][512];  // [dbuf][hi/lo][kstep][lane*8+j] = 64 KB
  __shared__ float e2s[NCW];              // 4 KB
  __shared__ int idx_s[128];

  const int t = threadIdx.x;
  const int w = t >> 6, l = t & 63;
  const int lc = l & 31, lh = l >> 5;
  const int row0 = blockIdx.x * 128 + w * 32;

  // e2 -> LDS
  *(float4*)&e2s[t * 4] = *(const float4*)&e2g[t * 4];

  // ---- load this wave's 32 rows of x as A-fragments, split hi/lo fp16 ----
  // A-frag (32x32x16): lane l holds A[row=l&31][k = kk*16 + (l>>5)*8 + j]
  f16x8 xh[NK], xl[NK];
  float x2p = 0.f;
  const float* xp = x + (size_t)(row0 + lc) * D + lh * 8;
#pragma unroll
  for (int kk = 0; kk < NK; ++kk) {
    float4 a = *(const float4*)(xp + kk * 16);
    float4 b = *(const float4*)(xp + kk * 16 + 4);
    float va[8] = {a.x, a.y, a.z, a.w, b.x, b.y, b.z, b.w};
#pragma unroll
    for (int i = 0; i < 8; ++i) {
      float v = va[i];
      _Float16 h = (_Float16)v;
      float r = v - (float)h;
      xh[kk][i] = h;
      xl[kk][i] = (_Float16)(r * 4096.0f);
      x2p = fmaf(v, v, x2p);
    }
  }

  // staging helper: chunk c -> buffer b (32 KB via 8 global_load_lds / thread)
  auto stage = [&](int c, int b) {
#pragma unroll
    for (int rr = 0; rr < 4; ++rr) {
      int kk = rr * 4 + w;  // wave-uniform
      size_t goff = ((size_t)c * NK + kk) * 512 + (size_t)l * 8;
      gl_lds16(ehf + goff, &eb[b][0][kk][0]);
      gl_lds16(elf + goff, &eb[b][1][kk][0]);
    }
  };

  stage(0, 0);
  __syncthreads();  // drains vmcnt -> chunk 0 + e2s ready

  float minv[16], mini[16], minv2[16];
#pragma unroll
  for (int r = 0; r < 16; ++r) { minv[r] = 3.4e38f; mini[r] = 0.f; minv2[r] = 3.4e38f; }

  for (int c = 0; c < NCHUNK; ++c) {
    const int buf = c & 1;
    if (c + 1 < NCHUNK) stage(c + 1, buf ^ 1);  // prefetch next chunk
    const float e2v = e2s[c * CHUNK + lc];

    f32x16 accA, accB;  // two chains: hi*hi ; (hi*lo' + lo'*hi)
#pragma unroll
    for (int r = 0; r < 16; ++r) { accA[r] = 0.f; accB[r] = 0.f; }
#pragma unroll
    for (int kk = 0; kk < NK; ++kk) {
      f16x8 bh = *(const f16x8*)&eb[buf][0][kk][l * 8];
      f16x8 bl = *(const f16x8*)&eb[buf][1][kk][l * 8];
      accA = __builtin_amdgcn_mfma_f32_32x32x16_f16(xh[kk], bh, accA, 0, 0, 0);
      accB = __builtin_amdgcn_mfma_f32_32x32x16_f16(xh[kk], bl, accB, 0, 0, 0);
      accB = __builtin_amdgcn_mfma_f32_32x32x16_f16(xl[kk], bh, accB, 0, 0, 0);
    }
    const float colf = (float)(c * CHUNK + lc);
#pragma unroll
    for (int r = 0; r < 16; ++r) {
      float dot = fmaf(accB[r], (1.0f / 4096.0f), accA[r]);
      float tt = fmaf(-2.0f, dot, e2v);  // e2 - 2*dot (x2 row-constant, dropped)
      bool b1 = tt < minv[r];
      float nm2 = b1 ? minv[r] : fminf(tt, minv2[r]);
      minv2[r] = nm2;
      minv[r] = b1 ? tt : minv[r];
      mini[r] = b1 ? colf : mini[r];
    }
    __syncthreads();  // staged chunk complete; safe to reuse buffers
  }

  // ---- reduce argmin+margin across 32 col-lanes ----
  // C/D: col=l&31, row=(reg&3)+8*(reg>>2)+4*lh
#pragma unroll
  for (int s = 1; s < 32; s <<= 1) {
#pragma unroll
    for (int r = 0; r < 16; ++r) {
      float v2 = __shfl_xor(minv[r], s);
      float i2 = __shfl_xor(mini[r], s);
      float w2 = __shfl_xor(minv2[r], s);
      float nm2 = fminf(fminf(minv2[r], w2), fmaxf(minv[r], v2));
      bool take = (v2 < minv[r]) || (v2 == minv[r] && i2 < mini[r]);
      minv[r] = take ? v2 : minv[r];
      mini[r] = take ? i2 : mini[r];
      minv2[r] = nm2;
    }
  }
  // lane l takes row r = l&31 (swap halves so each lane holds its row's result)
  const int r = lc;
  const int reg = (r & 3) | ((r >> 3) << 2);
  const int hneed = (r >> 2) & 1;
  float mv = minv[reg], mi = mini[reg], m2 = minv2[reg];
  float mvx = __shfl_xor(mv, 32), mix = __shfl_xor(mi, 32), m2x = __shfl_xor(m2, 32);
  if (hneed != lh) { mv = mvx; mi = mix; m2 = m2x; }
  const float x2row = x2p + __shfl_xor(x2p, 32);

  // loss: sum over rows of dist = x2 + t_min ; scale 1.2/numel
  float lossp = (l < 32) ? (x2row + mv) : 0.f;
#pragma unroll
  for (int s = 1; s < 64; s <<= 1) lossp += __shfl_xor(lossp, s);

  const int idx = (int)mi;
  if (l < 32) {
    out_idx[row0 + r] = mi;  // output buffer read as float32
    atomicAdd(&out_usage[idx], 1.0f);
    idx_s[w * 32 + r] = idx;
    if (m2 - mv < TAU) {  // near-tie: queue for exact fp64 re-resolution
      int pos = atomicAdd(flag_cnt, 1);
      if (pos < FCAP) flags[pos] = make_int2(row0 + r, idx);
    }
  }
  if (l == 0) atomicAdd(out_loss, lossp * (1.2f / 33554432.0f));
  __syncthreads();

  // ---- values_st = emb[idx] (coalesced row copy; emb is L2-hot) ----
#pragma unroll 4
  for (int rr = 0; rr < 32; ++rr) {
    int id = idx_s[w * 32 + rr];
    float4 v = *(const float4*)(emb + (size_t)id * D + l * 4);
    *(float4*)(out_val + (size_t)(row0 + rr) * D + l * 4) = v;
  }
}

// ---------------- refine: exact fp64 argmin for near-tie rows ----------------
__global__ __launch_bounds__(256) void vq_refine(
    const float* __restrict__ x, const float* __restrict__ emb,
    const int* __restrict__ flag_cnt, const int2* __restrict__ flags,
    float* __restrict__ out_val, float* __restrict__ out_idx,
    float* __restrict__ out_usage) {
  __shared__ float xs[D];
  __shared__ double bd[256];
  __shared__ int bi[256];
  const int t = threadIdx.x;
  const int cnt = min(*flag_cnt, FCAP);
  for (int f = blockIdx.x; f < cnt; f += gridDim.x) {
    __syncthreads();  // protect xs/bd reuse across grid-stride iterations
    const int row = flags[f].x, old_idx = flags[f].y;
    xs[t] = x[(size_t)row * D + t];
    __syncthreads();
    double best = 1.0e300; int bk = 0;
#pragma unroll
    for (int s = 0; s < 4; ++s) {
      const int k = t + s * 256;
      const float* ep = emb + (size_t)k * D;
      double a0 = 0.0, a1 = 0.0;
      for (int d = 0; d < D; d += 2) {
        double d0 = (double)xs[d] - (double)ep[d];
        double d1 = (double)xs[d + 1] - (double)ep[d + 1];
        a0 = fma(d0, d0, a0);
        a1 = fma(d1, d1, a1);
      }
      double acc = a0 + a1;
      if (acc < best || (acc == best && k < bk)) { best = acc; bk = k; }
    }
    bd[t] = best; bi[t] = bk;
    __syncthreads();
    if (t == 0) {
      double b = bd[0]; int k = bi[0];
      for (int i = 1; i < 256; ++i)
        if (bd[i] < b || (bd[i] == b && bi[i] < k)) { b = bd[i]; k = bi[i]; }
      bi[0] = k;
    }
    __syncthreads();
    const int nk = bi[0];
    if (t == 0 && nk != old_idx) {
      out_idx[row] = (float)nk;
      atomicAdd(&out_usage[old_idx], -1.0f);
      atomicAdd(&out_usage[nk], 1.0f);
    }
    // rewrite values row (unconditional; same values if unchanged)
    out_val[(size_t)row * D + t] = emb[(size_t)nk * D + t];
  }
}

extern "C" void kernel_launch(void* const* d_in, const int* in_sizes, int n_in,
                              void* d_out, int out_size, void* d_ws, size_t ws_size,
                              hipStream_t stream) {
  (void)n_in; (void)out_size; (void)ws_size;
  const float* x = (const float*)d_in[0];
  const float* emb = (const float*)d_in[1];

  const int n_xelem = in_sizes[0];       // 32*4096*256
  const int n_rows = n_xelem / D;        // 131072

  float* out = (float*)d_out;
  float* out_val = out;
  float* out_idx = out + n_xelem;
  float* out_loss = out_idx + n_rows;
  float* out_usage = out_loss + 1;

  _Float16* ehf = (_Float16*)d_ws;
  _Float16* elf = ehf + (size_t)NCHUNK * NK * 512;
  float* e2 = (float*)(elf + (size_t)NCHUNK * NK * 512);
  int* flag_cnt = (int*)(e2 + NCW);
  int2* flags = (int2*)(flag_cnt + 2);   // 8-byte aligned

  // zero loss + usages (harness poisons d_out/d_ws with 0xAA)
  hipMemsetAsync(out_loss, 0, (1 + NCW) * sizeof(float), stream);
  hipMemsetAsync(flag_cnt, 0, sizeof(int), stream);

  vq_prep<<<dim3(NCW / 4), dim3(256), 0, stream>>>(emb, ehf, elf, e2);
  vq_main<<<dim3(n_rows / 128), dim3(256), 0, stream>>>(
      x, emb, ehf, elf, e2, out_val, out_idx, out_loss, out_usage,
      flag_cnt, flags);
  vq_refine<<<dim3(512), dim3(256), 0, stream>>>(
      x, emb, flag_cnt, flags, out_val, out_idx, out_usage);
}